// Round 9
// baseline (142.895 us; speedup 1.0000x reference)
//
#include <hip/hip_runtime.h>

#define HW_    56
#define C_     128
#define SHIFT_ 3
#define NH_    4
#define NT_    49

typedef __attribute__((ext_vector_type(8))) __bf16 bf16x8;
typedef __attribute__((ext_vector_type(4))) float  f32x4;
typedef __attribute__((ext_vector_type(4))) short  s16x4;

// d_ws layout:
//   shorts [0, 65536)      : wT[384][128] (oc-major) then wpT[128][128]
//   bytes  [131072, +3.2MB): f32 cb[wpos=64][h=4][q=49][k=64]  (bias+mask, post-softmax)
#define WS_CB_BYTE  131072
#define CB_ELEMS    (64 * 4 * 49 * 64)

// LDS 29440 B.
// [0, 12544):  X [16 g][49 tok][16B] stride 784, identity (conflict-free:
//              fixed g per quarter-wave, rows contiguous). Reads to row 63
//              spill into [12544,12800) pad / V region: in-bounds garbage
//              feeding discarded columns only. After b2, X2 (attn out)
//              overlays with the SAME layout (g = d>>3).
// [12800, 29184): V per head h at VB+h*4096, FRAG-LINEAR for x16 PV:
//              frag(mtd*4+kt) = 512B, element = lane*8 + j*2. va reads are
//              fully linear ds_read_b64 (zero conflict). Keys 49..63
//              ZERO-FILLED at write (PV reduction axis: NaN*0=NaN!).
// [29184, 29380): int toff[49] (token -> gh*56+gw, rolled).
// Q, K, P: REGISTER-RESIDENT (x16 MFMA k=4lg+j matches C-layout 4-chunks).
#define XB    0
#define VB    12800
#define TOFFB 29184
#define SMEMB 29440

__device__ __forceinline__ int q4(int g, int tok) { return g * 784 + (tok << 4); }
__device__ __forceinline__ unsigned short bfbits(float f) {
    __bf16 h = (__bf16)f;
    union { __bf16 b; unsigned short u; } c; c.b = h; return c.u;
}
__device__ __forceinline__ int region(int c) { return c < 49 ? 0 : (c < 53 ? 1 : 2); }

// ---- prep 1: transpose + bf16-convert weights ----
__global__ void prep_weights(const float* __restrict__ wq, const float* __restrict__ wp,
                             unsigned short* __restrict__ ws) {
    int i = blockIdx.x * 256 + threadIdx.x;
    if (i < 49152) {
        int oc = i >> 7, ic = i & 127;
        ws[i] = bfbits(wq[ic * 384 + oc]);
    } else if (i < 65536) {
        int j = i - 49152;
        int oc = j >> 7, ic = j & 127;
        ws[i] = bfbits(wp[ic * 128 + oc]);
    }
}

// ---- prep 2: combined post-softmax bias + shifted-window mask ----
__global__ void prep_bias(const float* __restrict__ rel_table, float* __restrict__ cb) {
    int i = blockIdx.x * 256 + threadIdx.x;
    if (i >= CB_ELEMS) return;
    int k = i & 63;
    int t = i >> 6;          // (wpos*4 + h)*49 + q
    int q = t % 49;
    int u = t / 49;
    int h = u & 3;
    int wpos = u >> 2;
    float v = 0.f;
    if (k < 49) {
        int iq = q / 7, jq = q - 7 * iq;
        int ik = k / 7, jk = k - 7 * ik;
        int wi = wpos >> 3, wj = wpos & 7;
        v = rel_table[((iq - ik + 6) * 13 + (jq - jk + 6)) * NH_ + h];
        int rq = region(wi * 7 + iq) * 3 + region(wj * 7 + jq);
        int rk = region(wi * 7 + ik) * 3 + region(wj * 7 + jk);
        if (rq != rk) v -= 100.0f;
    }
    cb[i] = v;
}

__global__ __launch_bounds__(256, 4)
void swin_fused(const float* __restrict__ x,
                const float* __restrict__ b_qkv,
                const float* __restrict__ b_proj,
                const unsigned short* __restrict__ wsb,
                const float* __restrict__ cb,
                float* __restrict__ out)
{
    extern __shared__ char smc[];
    const __bf16* wt  = (const __bf16*)wsb;           // [384][128]
    const __bf16* wpt = (const __bf16*)(wsb + 49152); // [128][128]

    const int tid = threadIdx.x;
    const int bn  = blockIdx.x;
    const int b   = bn >> 6;
    const int wi  = (bn >> 3) & 7;
    const int wj  = bn & 7;

    const int w  = tid >> 6;        // wave id = head id
    const int lr = tid & 15;        // lane % 16
    const int lg = (tid & 63) >> 4; // lane / 16

    // token -> rolled spatial offset table (read after b3 by epilogue)
    if (tid < NT_) {
        const int i1 = tid / 7, j1 = tid - 7 * i1;
        int gh = wi * 7 + i1 + SHIFT_; if (gh >= HW_) gh -= HW_;
        int gw = wj * 7 + j1 + SHIFT_; if (gw >= HW_) gw -= HW_;
        ((int*)(smc + TOFFB))[tid] = gh * HW_ + gw;
    }

    // ---------------- phase 1: x -> X (bf16 frag-order, 49 rows) ----------------
    for (int idx = tid; idx < 49 * 16; idx += 256) {
        const int g = idx & 15, tok = idx >> 4;
        const int i1 = tok / 7, j1 = tok - 7 * i1;
        int gh = wi * 7 + i1 + SHIFT_; if (gh >= HW_) gh -= HW_;
        int gw = wj * 7 + j1 + SHIFT_; if (gw >= HW_) gw -= HW_;
        const float* px = x + (((size_t)(b * HW_ + gh)) * HW_ + gw) * C_ + g * 8;
        float4 a0 = *(const float4*)(px);
        float4 a1 = *(const float4*)(px + 4);
        union { bf16x8 v; __bf16 e[8]; } u;
        u.e[0] = (__bf16)a0.x; u.e[1] = (__bf16)a0.y;
        u.e[2] = (__bf16)a0.z; u.e[3] = (__bf16)a0.w;
        u.e[4] = (__bf16)a1.x; u.e[5] = (__bf16)a1.y;
        u.e[6] = (__bf16)a1.z; u.e[7] = (__bf16)a1.w;
        *(bf16x8*)(smc + XB + q4(g, tok)) = u.v;
    }
    __syncthreads();  // b1: X (and toff) ready

    // ---------------- phase 2: QKV, wave w owns head w; Q/K -> registers ----------------
    // pass0: {2w (q d0-15), 2w+1 (q d16-31), 16+2w (v d0-15)}
    // pass1: {8+2w (k d0-15), 8+2w+1 (k d16-31), 16+2w+1 (v d16-31)}
    const float qscale = 0.17677669529663687f;
    const int vb = VB + w * 4096;
    s16x4 qf[2][4], ka[2][4];   // x16 fragments: elem j = key/d offset 4*lg+j

    #pragma unroll
    for (int pass = 0; pass < 2; ++pass) {
        const int ma = pass * 8 + 2 * w;
        const int mv = 16 + 2 * w + pass;
        f32x4 acc[3][4];
        #pragma unroll
        for (int i = 0; i < 3; ++i) {
            const int mt = (i < 2) ? (ma + i) : mv;
            const f32x4 bv = *(const f32x4*)(b_qkv + mt * 16 + lg * 4);
            #pragma unroll
            for (int nt = 0; nt < 4; ++nt) acc[i][nt] = bv;
        }
        #pragma unroll
        for (int ks = 0; ks < 4; ++ks) {
            bf16x8 bfr[4];
            #pragma unroll
            for (int nt = 0; nt < 4; ++nt)   // rows>=49: in-bounds garbage, cols discarded
                bfr[nt] = *(const bf16x8*)(smc + XB + q4(ks * 4 + lg, nt * 16 + lr));
            #pragma unroll
            for (int i = 0; i < 3; ++i) {
                const int mt = (i < 2) ? (ma + i) : mv;
                bf16x8 afr = *(const bf16x8*)(wt + (mt * 16 + lr) * 128 + ks * 32 + lg * 8);
                #pragma unroll
                for (int nt = 0; nt < 4; ++nt)
                    acc[i][nt] = __builtin_amdgcn_mfma_f32_16x16x32_bf16(afr, bfr[nt], acc[i][nt], 0, 0, 0);
            }
        }
        // pack q (pass0, scaled) / k (pass1) directly into x16 fragments
        #pragma unroll
        for (int kt = 0; kt < 2; ++kt)
            #pragma unroll
            for (int nt = 0; nt < 4; ++nt) {
                union { s16x4 v; __bf16 e[4]; } u;
                #pragma unroll
                for (int r = 0; r < 4; ++r)
                    u.e[r] = (__bf16)(pass ? acc[kt][nt][r] : acc[kt][nt][r] * qscale);
                if (pass) ka[kt][nt] = u.v; else qf[kt][nt] = u.v;
            }
        // V scatter, frag-linear; keys 49..63 ZERO (PV reduction axis)
        #pragma unroll
        for (int nt = 0; nt < 4; ++nt) {
            const int key = nt * 16 + lr;
            #pragma unroll
            for (int r = 0; r < 4; ++r) {
                const unsigned short val =
                    (key < NT_) ? bfbits(acc[2][nt][r]) : (unsigned short)0;
                *(unsigned short*)(smc + vb + (pass * 4 + nt) * 512
                      + ((lg * 4 + r) + ((lr >> 2) << 4)) * 8 + ((lr & 3) << 1)) = val;
            }
        }
    }
    __syncthreads();  // b2: all X reads done -> X2 may overlay X

    // ---------------- phase 3: attention, fully wave-private ----------------
    // va: 8 linear ds_read_b64 (own V, same-wave write->read ordered by lgkmcnt)
    s16x4 va[2][4];
    #pragma unroll
    for (int mtd = 0; mtd < 2; ++mtd)
        #pragma unroll
        for (int kt = 0; kt < 4; ++kt)
            va[mtd][kt] = *(const s16x4*)(smc + vb + (mtd * 4 + kt) * 512 + (tid & 63) * 8);

    const float* cbw = cb + (((size_t)(wi * 8 + wj) * 4 + w) * 49) * 64;
    f32x4 o[2][4];
    #pragma unroll
    for (int mtd = 0; mtd < 2; ++mtd)
        #pragma unroll
        for (int nt = 0; nt < 4; ++nt) { f32x4 z = {0.f,0.f,0.f,0.f}; o[mtd][nt] = z; }

    #pragma unroll
    for (int nt = 0; nt < 4; ++nt) {
        // S^T tile column: keys x q for this q-tile (K=16 MFMAs, reg operands)
        f32x4 sn[4];
        #pragma unroll
        for (int mt = 0; mt < 4; ++mt) {
            f32x4 z = {0.f, 0.f, 0.f, 0.f};
            z = __builtin_amdgcn_mfma_f32_16x16x16bf16_1k(ka[0][mt], qf[0][nt], z, 0, 0, 0);
            sn[mt] = __builtin_amdgcn_mfma_f32_16x16x16bf16_1k(ka[1][mt], qf[1][nt], z, 0, 0, 0);
        }
        // softmax over keys (valid: keys 0..48)
        float mx = -3.0e38f;
        #pragma unroll
        for (int mt = 0; mt < 3; ++mt)
            #pragma unroll
            for (int r = 0; r < 4; ++r) mx = fmaxf(mx, sn[mt][r]);
        if (lg == 0) mx = fmaxf(mx, sn[3][0]);
        mx = fmaxf(mx, __shfl_xor(mx, 16));
        mx = fmaxf(mx, __shfl_xor(mx, 32));
        float sum = 0.f;
        #pragma unroll
        for (int mt = 0; mt < 3; ++mt)
            #pragma unroll
            for (int r = 0; r < 4; ++r) {
                const float e = __expf(sn[mt][r] - mx);
                sn[mt][r] = e; sum += e;
            }
        {
            const float e = (lg == 0) ? __expf(sn[3][0] - mx) : 0.f;
            sn[3][0] = e;
            sum += e;
        }
        sum += __shfl_xor(sum, 16);
        sum += __shfl_xor(sum, 32);
        const float rs = 1.0f / sum;

        const int q  = nt * 16 + lr;
        const int qc = (q < NT_) ? q : 48;
        const float* cbq = cbw + qc * 64;

        // post-softmax bias+mask, pack P directly into x16 B-fragments (NO LDS)
        s16x4 pf[4];
        #pragma unroll
        for (int mt = 0; mt < 4; ++mt) {
            const f32x4 bv = *(const f32x4*)(cbq + mt * 16 + lg * 4);
            union { s16x4 v; __bf16 e[4]; } u;
            #pragma unroll
            for (int r = 0; r < 4; ++r) {
                const bool valid = (mt < 3) || (lg == 0 && r == 0);
                const float p = fmaf(sn[mt][r], rs, bv[r]);
                u.e[r] = valid ? (__bf16)p : (__bf16)0.0f;
            }
            pf[mt] = u.v;
        }
        // PV accumulate (K=16 over 4 key-tiles)
        #pragma unroll
        for (int mtd = 0; mtd < 2; ++mtd)
            #pragma unroll
            for (int kt = 0; kt < 4; ++kt)
                o[mtd][nt] = __builtin_amdgcn_mfma_f32_16x16x16bf16_1k(va[mtd][kt], pf[kt], o[mtd][nt], 0, 0, 0);
    }

    // X2 scatter into X region (own head's g-range, post-b2)
    #pragma unroll
    for (int mtd = 0; mtd < 2; ++mtd) {
        const int g = w * 4 + mtd * 2 + (lg >> 1);
        const int inner = (lg & 1) << 3;
        #pragma unroll
        for (int nt = 0; nt < 4; ++nt) {
            const int tok = nt * 16 + lr;
            if (tok < NT_) {
                union { short4 s4; __bf16 e[4]; } pk;
                #pragma unroll
                for (int r = 0; r < 4; ++r) pk.e[r] = (__bf16)o[mtd][nt][r];
                *(short4*)(smc + XB + q4(g, tok) + inner) = pk.s4;
            }
        }
    }

    // hoist proj weight fragments (global, no LDS dep) before the barrier
    bf16x8 bfpR[2][4];
    #pragma unroll
    for (int ntl = 0; ntl < 2; ++ntl)
        #pragma unroll
        for (int ks = 0; ks < 4; ++ks)
            bfpR[ntl][ks] = *(const bf16x8*)(wpt + ((w * 2 + ntl) * 16 + lr) * 128 + ks * 32 + lg * 8);
    __syncthreads();  // b3: all heads' X2 complete

    // ---------------- phase 4: proj = X2 @ Wp + store ----------------
    {
        const int* toff = (const int*)(smc + TOFFB);
        f32x4 pacc[4][2];
        #pragma unroll
        for (int ntl = 0; ntl < 2; ++ntl) {
            const float bv = b_proj[(w * 2 + ntl) * 16 + lr];
            #pragma unroll
            for (int mt = 0; mt < 4; ++mt) {
                f32x4 v = {bv, bv, bv, bv};
                pacc[mt][ntl] = v;
            }
        }
        #pragma unroll
        for (int ks = 0; ks < 4; ++ks) {
            bf16x8 af[4];
            #pragma unroll
            for (int mt = 0; mt < 4; ++mt)
                af[mt] = *(const bf16x8*)(smc + XB + q4(ks * 4 + lg, mt * 16 + lr));
            #pragma unroll
            for (int mt = 0; mt < 4; ++mt)
                #pragma unroll
                for (int ntl = 0; ntl < 2; ++ntl)
                    pacc[mt][ntl] = __builtin_amdgcn_mfma_f32_16x16x32_bf16(af[mt], bfpR[ntl][ks], pacc[mt][ntl], 0, 0, 0);
        }
        #pragma unroll
        for (int mt = 0; mt < 4; ++mt)
            #pragma unroll
            for (int r = 0; r < 4; ++r) {
                const int tok = mt * 16 + lg * 4 + r;
                if (tok < NT_) {
                    float* po = out + (((size_t)b * (HW_ * HW_)) + toff[tok]) * C_;
                    #pragma unroll
                    for (int ntl = 0; ntl < 2; ++ntl)
                        po[(w * 2 + ntl) * 16 + lr] = pacc[mt][ntl][r];
                }
            }
    }
}

extern "C" void kernel_launch(void* const* d_in, const int* in_sizes, int n_in,
                              void* d_out, int out_size, void* d_ws, size_t ws_size,
                              hipStream_t stream) {
    const float* x      = (const float*)d_in[0];
    const float* w_qkv  = (const float*)d_in[1];
    const float* b_qkv  = (const float*)d_in[2];
    const float* w_proj = (const float*)d_in[3];
    const float* b_proj = (const float*)d_in[4];
    const float* rel    = (const float*)d_in[5];
    float* outp = (float*)d_out;
    unsigned short* wsb = (unsigned short*)d_ws;
    float* cbp = (float*)((char*)d_ws + WS_CB_BYTE);

    hipLaunchKernelGGL(prep_weights, dim3(256), dim3(256), 0, stream, w_qkv, w_proj, wsb);
    hipLaunchKernelGGL(prep_bias, dim3((CB_ELEMS + 255) / 256), dim3(256), 0, stream, rel, cbp);
    hipLaunchKernelGGL(swin_fused, dim3(4096), dim3(256), SMEMB, stream,
                       x, b_qkv, b_proj, wsb, cbp, outp);
}